// Round 2
// baseline (283.812 us; speedup 1.0000x reference)
//
#include <hip/hip_runtime.h>

#define NN 50000
#define NE 800000
#define GEMM_BLOCKS 782      // ceil(50000/64)
#define HIST_BLOCKS 512

typedef unsigned short ushort_t;

__device__ __forceinline__ ushort_t f2bf(float f) {
    unsigned u = __float_as_uint(f);
    unsigned r = (u + 0x7fffu + ((u >> 16) & 1u)) >> 16;   // RNE
    return (ushort_t)r;
}
__device__ __forceinline__ float bf2f(ushort_t h) {
    return __uint_as_float(((unsigned)h) << 16);
}
__device__ __forceinline__ float lrelu(float v) { return (v > 0.f) ? v : 0.2f * v; }

// ---- K1: fused  X = nodes@W + b (store bf16), a01 = lrelu(x·alpha) per node, + edge histogram
__global__ __launch_bounds__(256) void gemm_hist(
    const float* __restrict__ A,     // nodes [NN][128]
    const float* __restrict__ W,     // [128][128]
    const float* __restrict__ bl,    // [128]
    const float* __restrict__ alpha, // [256] (only first 128 used)
    const int*   __restrict__ rcv,   // [NE]
    ushort_t*    __restrict__ Xb,    // bf16 [NN][128]
    float2*      __restrict__ a01,   // [NN]
    int*         __restrict__ cnt)   // [NN]
{
    if (blockIdx.x >= GEMM_BLOCKS) {
        // ---- histogram blocks (independent work, overlapped with GEMM) ----
        int i = (blockIdx.x - GEMM_BLOCKS) * 256 + threadIdx.x;
        const int stride = HIST_BLOCKS * 256;
        for (; i < NE; i += stride) atomicAdd(&cnt[rcv[i]], 1);
        return;
    }

    __shared__ float As[32][68];    // transposed A tile: As[k][row]
    __shared__ float Bs[32][132];   // B tile: Bs[k][col]
    const int tid = threadIdx.x;
    const int tx = tid & 15, ty = tid >> 4;
    const int r0 = blockIdx.x * 64;
    float acc[4][8];
#pragma unroll
    for (int i = 0; i < 4; ++i)
#pragma unroll
        for (int j = 0; j < 8; ++j) acc[i][j] = 0.f;

    for (int k0 = 0; k0 < 128; k0 += 32) {
#pragma unroll
        for (int l = 0; l < 2; ++l) {
            int id = tid + l * 256;
            int row = id >> 3, c4 = id & 7;
            int gr = r0 + row;
            float4 v = make_float4(0.f, 0.f, 0.f, 0.f);
            if (gr < NN) v = *(const float4*)(A + gr * 128 + k0 + c4 * 4);
            As[c4 * 4 + 0][row] = v.x; As[c4 * 4 + 1][row] = v.y;
            As[c4 * 4 + 2][row] = v.z; As[c4 * 4 + 3][row] = v.w;
        }
#pragma unroll
        for (int l = 0; l < 4; ++l) {
            int id = tid + l * 256;
            int kk = id >> 5, c4 = id & 31;
            *(float4*)&Bs[kk][c4 * 4] = *(const float4*)(W + (k0 + kk) * 128 + c4 * 4);
        }
        __syncthreads();
#pragma unroll
        for (int kk = 0; kk < 32; ++kk) {
            float4 a4 = *(float4*)&As[kk][ty * 4];
            float4 b0 = *(float4*)&Bs[kk][tx * 4];
            float4 b1 = *(float4*)&Bs[kk][64 + tx * 4];
            float av[4] = {a4.x, a4.y, a4.z, a4.w};
            float bv[8] = {b0.x, b0.y, b0.z, b0.w, b1.x, b1.y, b1.z, b1.w};
#pragma unroll
            for (int i = 0; i < 4; ++i)
#pragma unroll
                for (int j = 0; j < 8; ++j)
                    acc[i][j] = fmaf(av[i], bv[j], acc[i][j]);
        }
        __syncthreads();
    }

    // epilogue: +bias, store bf16, per-row alpha dots reduced across the 16 tx lanes
    float4 blo = *(const float4*)(bl + tx * 4);
    float4 bhi = *(const float4*)(bl + 64 + tx * 4);
    float4 alo = *(const float4*)(alpha + tx * 4);        // head0 coeffs, ch tx*4..+3
    float4 ahi = *(const float4*)(alpha + 64 + tx * 4);   // head1 coeffs, ch 64+tx*4..+3
#pragma unroll
    for (int i = 0; i < 4; ++i) {
        int gr = r0 + ty * 4 + i;
        bool ok = (gr < NN);
        float o0 = acc[i][0] + blo.x, o1 = acc[i][1] + blo.y;
        float o2 = acc[i][2] + blo.z, o3 = acc[i][3] + blo.w;
        float o4 = acc[i][4] + bhi.x, o5 = acc[i][5] + bhi.y;
        float o6 = acc[i][6] + bhi.z, o7 = acc[i][7] + bhi.w;
        if (ok) {
            ushort4 p0, p1;
            p0.x = f2bf(o0); p0.y = f2bf(o1); p0.z = f2bf(o2); p0.w = f2bf(o3);
            p1.x = f2bf(o4); p1.y = f2bf(o5); p1.z = f2bf(o6); p1.w = f2bf(o7);
            *(ushort4*)(Xb + (size_t)gr * 128 + tx * 4) = p0;
            *(ushort4*)(Xb + (size_t)gr * 128 + 64 + tx * 4) = p1;
        }
        float v0 = o0 * alo.x + o1 * alo.y + o2 * alo.z + o3 * alo.w;
        float v1 = o4 * ahi.x + o5 * ahi.y + o6 * ahi.z + o7 * ahi.w;
#pragma unroll
        for (int d = 1; d < 16; d <<= 1) {
            v0 += __shfl_xor(v0, d);
            v1 += __shfl_xor(v1, d);
        }
        if (ok && tx == 0) a01[gr] = make_float2(lrelu(v0), lrelu(v1));
    }
}

// ---- K2: exclusive scan of cnt -> off, zero cnt (single block, 2 barriers total)
__global__ __launch_bounds__(1024) void exscan(int* __restrict__ cnt, int* __restrict__ off)
{
    __shared__ int wsum[16];
    const int t = threadIdx.x, lane = t & 63, wid = t >> 6;
    const int CH = 49;                       // 1024*49 >= 50000
    const int base = t * CH;
    int s = 0;
#pragma unroll 1
    for (int k = 0; k < CH; ++k) {
        int i = base + k;
        if (i < NN) s += cnt[i];
    }
    int incl = s;
#pragma unroll
    for (int d = 1; d < 64; d <<= 1) {
        int u = __shfl_up(incl, d);
        if (lane >= d) incl += u;
    }
    if (lane == 63) wsum[wid] = incl;
    __syncthreads();
    if (t < 16) {
        int w = wsum[t], wi = w;
#pragma unroll
        for (int d = 1; d < 16; d <<= 1) {
            int u = __shfl_up(wi, d);
            if (t >= d) wi += u;
        }
        wsum[t] = wi - w;                    // exclusive wave prefix
    }
    __syncthreads();
    int run = wsum[wid] + (incl - s);
#pragma unroll 1
    for (int k = 0; k < CH; ++k) {
        int i = base + k;
        if (i < NN) { off[i] = run; run += cnt[i]; cnt[i] = 0; }
    }
    if (t == 0) off[NN] = NE;
}

// ---- K3: scatter sender ids into CSR order (cur == cnt, zeroed by exscan)
__global__ __launch_bounds__(256) void scatter(
    const int* __restrict__ snd, const int* __restrict__ rcv,
    const int* __restrict__ off, int* __restrict__ cur, int* __restrict__ srt)
{
    int i = blockIdx.x * 256 + threadIdx.x;
    if (i >= NE) return;
    int r = rcv[i];
    int p = off[r] + atomicAdd(&cur[r], 1);
    srt[p] = snd[i];
}

// ---- K4: per-node aggregation. lane -> channels {2*lane, 2*lane+1}.
// lanes 0-15: head0 softmax; 16-31: head1 softmax; 32-63: heads 2/3 (uniform mean).
__global__ __launch_bounds__(256) void aggregate(
    const ushort_t* __restrict__ Xb, const float2* __restrict__ a01,
    const int* __restrict__ off, const int* __restrict__ srt,
    const float* __restrict__ bias, float* __restrict__ out)
{
    const int n = blockIdx.x * 4 + (threadIdx.x >> 6);
    const int lane = threadIdx.x & 63;
    const int beg = off[n];
    const int deg = off[n + 1] - beg;
    const int total = deg + 1;               // + self loop
    const bool softlane = (lane < 32);

    float accx = 0.f, accy = 0.f, D = 0.f;
    for (int base = 0; base < total; base += 64) {
        int idx = base + lane;
        int sj = (idx < deg) ? srt[beg + idx] : n;   // idx==deg -> self
        float2 w2 = a01[sj];                          // 64 gathers in parallel
        int cntc = min(64, total - base);
        for (int d = 0; d < cntc; ++d) {
            int   s   = __shfl(sj, d);
            float a0b = __shfl(w2.x, d);
            float a1b = __shfl(w2.y, d);
            float w   = __expf((lane < 16) ? a0b : a1b);   // no max: |logit| <= ~36, safe in fp32
            float ww  = softlane ? w : 1.0f;
            ushort2 xv = *(const ushort2*)(Xb + (size_t)s * 128 + 2 * lane);
            accx = fmaf(ww, bf2f(xv.x), accx);
            accy = fmaf(ww, bf2f(xv.y), accy);
            D += w;
        }
    }
    float scale = softlane ? (1.0f / D) : (1.0f / (float)total);
    float bx = bias[2 * lane], by = bias[2 * lane + 1];
    float2 o = make_float2(accx * scale + bx, accy * scale + by);
    *(float2*)(out + (size_t)n * 128 + 2 * lane) = o;
}

// ------------------------------------------------------------------------------
extern "C" void kernel_launch(void* const* d_in, const int* in_sizes, int n_in,
                              void* d_out, int out_size, void* d_ws, size_t ws_size,
                              hipStream_t stream)
{
    const float* nodes     = (const float*)d_in[0];
    const int*   senders   = (const int*)d_in[1];
    const int*   receivers = (const int*)d_in[2];
    const float* W         = (const float*)d_in[3];
    const float* b_lin     = (const float*)d_in[4];
    const float* alpha     = (const float*)d_in[5];
    const float* bias      = (const float*)d_in[6];
    float* out = (float*)d_out;

    char* ws = (char*)d_ws;
    ushort_t* Xb  = (ushort_t*)(ws);               // 12,800,000 B
    float2*   a01 = (float2*)  (ws + 12800000);    //    400,000 B
    int*      cnt = (int*)     (ws + 13200000);    //    200,000 B
    int*      off = (int*)     (ws + 13400000);    //    200,064 B (padded)
    int*      srt = (int*)     (ws + 13600064);    //  3,200,000 B

    hipMemsetAsync(cnt, 0, NN * sizeof(int), stream);
    gemm_hist<<<GEMM_BLOCKS + HIST_BLOCKS, 256, 0, stream>>>(
        nodes, W, b_lin, alpha, receivers, Xb, a01, cnt);
    exscan   <<<1, 1024, 0, stream>>>(cnt, off);
    scatter  <<<(NE + 255) / 256, 256, 0, stream>>>(senders, receivers, off, cnt, srt);
    aggregate<<<(NN + 3) / 4, 256, 0, stream>>>(Xb, a01, off, srt, bias, out);
}

// Round 3
// 175.361 us; speedup vs baseline: 1.6184x; 1.6184x over previous
//
#include <hip/hip_runtime.h>

#define NN 50000
#define NE 800000
#define GEMM_BLOCKS 782      // ceil(50000/64)
#define HIST_BLOCKS 512
#define SCAN_BLOCKS 49       // ceil(50000/1024)

typedef unsigned short ushort_t;

__device__ __forceinline__ ushort_t f2bf(float f) {
    unsigned u = __float_as_uint(f);
    unsigned r = (u + 0x7fffu + ((u >> 16) & 1u)) >> 16;   // RNE
    return (ushort_t)r;
}
__device__ __forceinline__ float bf2f(ushort_t h) {
    return __uint_as_float(((unsigned)h) << 16);
}
__device__ __forceinline__ float lrelu(float v) { return (v > 0.f) ? v : 0.2f * v; }

// ---- K1: fused  X = nodes@W + b (store bf16), a01 = lrelu(x·alpha) per node, + edge histogram
__global__ __launch_bounds__(256) void gemm_hist(
    const float* __restrict__ A,     // nodes [NN][128]
    const float* __restrict__ W,     // [128][128]
    const float* __restrict__ bl,    // [128]
    const float* __restrict__ alpha, // [256] (only first 128 used)
    const int*   __restrict__ rcv,   // [NE]
    ushort_t*    __restrict__ Xb,    // bf16 [NN][128]
    float2*      __restrict__ a01,   // [NN]
    int*         __restrict__ cnt)   // [NN]
{
    if (blockIdx.x >= GEMM_BLOCKS) {
        // ---- histogram blocks (independent work, overlapped with GEMM) ----
        int i = (blockIdx.x - GEMM_BLOCKS) * 256 + threadIdx.x;
        const int stride = HIST_BLOCKS * 256;
        for (; i < NE; i += stride) atomicAdd(&cnt[rcv[i]], 1);
        return;
    }

    __shared__ float As[32][68];    // transposed A tile: As[k][row]
    __shared__ float Bs[32][132];   // B tile: Bs[k][col]
    const int tid = threadIdx.x;
    const int tx = tid & 15, ty = tid >> 4;
    const int r0 = blockIdx.x * 64;
    float acc[4][8];
#pragma unroll
    for (int i = 0; i < 4; ++i)
#pragma unroll
        for (int j = 0; j < 8; ++j) acc[i][j] = 0.f;

    for (int k0 = 0; k0 < 128; k0 += 32) {
#pragma unroll
        for (int l = 0; l < 2; ++l) {
            int id = tid + l * 256;
            int row = id >> 3, c4 = id & 7;
            int gr = r0 + row;
            float4 v = make_float4(0.f, 0.f, 0.f, 0.f);
            if (gr < NN) v = *(const float4*)(A + gr * 128 + k0 + c4 * 4);
            As[c4 * 4 + 0][row] = v.x; As[c4 * 4 + 1][row] = v.y;
            As[c4 * 4 + 2][row] = v.z; As[c4 * 4 + 3][row] = v.w;
        }
#pragma unroll
        for (int l = 0; l < 4; ++l) {
            int id = tid + l * 256;
            int kk = id >> 5, c4 = id & 31;
            *(float4*)&Bs[kk][c4 * 4] = *(const float4*)(W + (k0 + kk) * 128 + c4 * 4);
        }
        __syncthreads();
#pragma unroll
        for (int kk = 0; kk < 32; ++kk) {
            float4 a4 = *(float4*)&As[kk][ty * 4];
            float4 b0 = *(float4*)&Bs[kk][tx * 4];
            float4 b1 = *(float4*)&Bs[kk][64 + tx * 4];
            float av[4] = {a4.x, a4.y, a4.z, a4.w};
            float bv[8] = {b0.x, b0.y, b0.z, b0.w, b1.x, b1.y, b1.z, b1.w};
#pragma unroll
            for (int i = 0; i < 4; ++i)
#pragma unroll
                for (int j = 0; j < 8; ++j)
                    acc[i][j] = fmaf(av[i], bv[j], acc[i][j]);
        }
        __syncthreads();
    }

    // epilogue: +bias, store bf16, per-row alpha dots reduced across the 16 tx lanes
    float4 blo = *(const float4*)(bl + tx * 4);
    float4 bhi = *(const float4*)(bl + 64 + tx * 4);
    float4 alo = *(const float4*)(alpha + tx * 4);        // head0 coeffs, ch tx*4..+3
    float4 ahi = *(const float4*)(alpha + 64 + tx * 4);   // head1 coeffs, ch 64+tx*4..+3
#pragma unroll
    for (int i = 0; i < 4; ++i) {
        int gr = r0 + ty * 4 + i;
        bool ok = (gr < NN);
        float o0 = acc[i][0] + blo.x, o1 = acc[i][1] + blo.y;
        float o2 = acc[i][2] + blo.z, o3 = acc[i][3] + blo.w;
        float o4 = acc[i][4] + bhi.x, o5 = acc[i][5] + bhi.y;
        float o6 = acc[i][6] + bhi.z, o7 = acc[i][7] + bhi.w;
        if (ok) {
            ushort4 p0, p1;
            p0.x = f2bf(o0); p0.y = f2bf(o1); p0.z = f2bf(o2); p0.w = f2bf(o3);
            p1.x = f2bf(o4); p1.y = f2bf(o5); p1.z = f2bf(o6); p1.w = f2bf(o7);
            *(ushort4*)(Xb + (size_t)gr * 128 + tx * 4) = p0;
            *(ushort4*)(Xb + (size_t)gr * 128 + 64 + tx * 4) = p1;
        }
        float v0 = o0 * alo.x + o1 * alo.y + o2 * alo.z + o3 * alo.w;
        float v1 = o4 * ahi.x + o5 * ahi.y + o6 * ahi.z + o7 * ahi.w;
#pragma unroll
        for (int d = 1; d < 16; d <<= 1) {
            v0 += __shfl_xor(v0, d);
            v1 += __shfl_xor(v1, d);
        }
        if (ok && tx == 0) a01[gr] = make_float2(lrelu(v0), lrelu(v1));
    }
}

// ---- K2a: block-local exclusive scan (49 blocks x 1024, coalesced) ----------
__global__ __launch_bounds__(1024) void scan_partial(
    const int* __restrict__ cnt, int* __restrict__ off, int* __restrict__ bsum)
{
    __shared__ int wsum[16];
    const int t = threadIdx.x, lane = t & 63, wid = t >> 6;
    const int i = blockIdx.x * 1024 + t;
    int v = (i < NN) ? cnt[i] : 0;
    int incl = v;
#pragma unroll
    for (int d = 1; d < 64; d <<= 1) {
        int u = __shfl_up(incl, d);
        if (lane >= d) incl += u;
    }
    if (lane == 63) wsum[wid] = incl;
    __syncthreads();
    if (t < 16) {
        int w = wsum[t], wi = w;
#pragma unroll
        for (int d = 1; d < 16; d <<= 1) {
            int u = __shfl_up(wi, d);
            if (t >= d) wi += u;
        }
        wsum[t] = wi - w;                    // exclusive wave prefix
    }
    __syncthreads();
    int ex = wsum[wid] + (incl - v);         // block-local exclusive prefix
    if (i < NN) off[i] = ex;
    if (t == 1023) bsum[blockIdx.x] = ex + v;  // block total
}

// ---- K2b: scan the 49 block totals (one wave) -------------------------------
__global__ __launch_bounds__(64) void scan_mid(int* __restrict__ bsum, int* __restrict__ boff,
                                               int* __restrict__ off)
{
    const int t = threadIdx.x;
    int v = (t < SCAN_BLOCKS) ? bsum[t] : 0;
    int incl = v;
#pragma unroll
    for (int d = 1; d < 64; d <<= 1) {
        int u = __shfl_up(incl, d);
        if (t >= d) incl += u;
    }
    if (t < SCAN_BLOCKS) boff[t] = incl - v;
    if (t == 0) off[NN] = NE;
}

// ---- K2c: add block offsets, zero cnt for scatter's cursor ------------------
__global__ __launch_bounds__(1024) void scan_add(
    int* __restrict__ off, const int* __restrict__ boff, int* __restrict__ cnt)
{
    const int i = blockIdx.x * 1024 + threadIdx.x;
    if (i < NN) { off[i] += boff[blockIdx.x]; cnt[i] = 0; }
}

// ---- K3: scatter sender ids into CSR order (cur == cnt, zeroed by scan_add)
__global__ __launch_bounds__(256) void scatter(
    const int* __restrict__ snd, const int* __restrict__ rcv,
    const int* __restrict__ off, int* __restrict__ cur, int* __restrict__ srt)
{
    int i = blockIdx.x * 256 + threadIdx.x;
    if (i >= NE) return;
    int r = rcv[i];
    int p = off[r] + atomicAdd(&cur[r], 1);
    srt[p] = snd[i];
}

// ---- K4: per-node aggregation. lane -> channels {2*lane, 2*lane+1}.
// lanes 0-15: head0 softmax; 16-31: head1 softmax; 32-63: heads 2/3 (uniform mean).
__global__ __launch_bounds__(256) void aggregate(
    const ushort_t* __restrict__ Xb, const float2* __restrict__ a01,
    const int* __restrict__ off, const int* __restrict__ srt,
    const float* __restrict__ bias, float* __restrict__ out)
{
    const int n = blockIdx.x * 4 + (threadIdx.x >> 6);
    const int lane = threadIdx.x & 63;
    const int beg = off[n];
    const int deg = off[n + 1] - beg;
    const int total = deg + 1;               // + self loop
    const bool softlane = (lane < 32);

    float accx = 0.f, accy = 0.f, D = 0.f;
    for (int base = 0; base < total; base += 64) {
        int idx = base + lane;
        int sj = (idx < deg) ? srt[beg + idx] : n;   // idx==deg -> self
        float2 w2 = a01[sj];                          // 64 gathers in parallel
        int cntc = min(64, total - base);
        for (int d = 0; d < cntc; ++d) {
            int   s   = __shfl(sj, d);
            float a0b = __shfl(w2.x, d);
            float a1b = __shfl(w2.y, d);
            float w   = __expf((lane < 16) ? a0b : a1b);   // no max: |logit| <= ~36, safe in fp32
            float ww  = softlane ? w : 1.0f;
            ushort2 xv = *(const ushort2*)(Xb + (size_t)s * 128 + 2 * lane);
            accx = fmaf(ww, bf2f(xv.x), accx);
            accy = fmaf(ww, bf2f(xv.y), accy);
            D += w;
        }
    }
    float scale = softlane ? (1.0f / D) : (1.0f / (float)total);
    float bx = bias[2 * lane], by = bias[2 * lane + 1];
    float2 o = make_float2(accx * scale + bx, accy * scale + by);
    *(float2*)(out + (size_t)n * 128 + 2 * lane) = o;
}

// ------------------------------------------------------------------------------
extern "C" void kernel_launch(void* const* d_in, const int* in_sizes, int n_in,
                              void* d_out, int out_size, void* d_ws, size_t ws_size,
                              hipStream_t stream)
{
    const float* nodes     = (const float*)d_in[0];
    const int*   senders   = (const int*)d_in[1];
    const int*   receivers = (const int*)d_in[2];
    const float* W         = (const float*)d_in[3];
    const float* b_lin     = (const float*)d_in[4];
    const float* alpha     = (const float*)d_in[5];
    const float* bias      = (const float*)d_in[6];
    float* out = (float*)d_out;

    char* ws = (char*)d_ws;
    ushort_t* Xb   = (ushort_t*)(ws);               // 12,800,000 B
    float2*   a01  = (float2*)  (ws + 12800000);    //    400,000 B
    int*      cnt  = (int*)     (ws + 13200000);    //    200,000 B
    int*      off  = (int*)     (ws + 13400000);    //    200,064 B (padded)
    int*      srt  = (int*)     (ws + 13600064);    //  3,200,000 B
    int*      bsum = (int*)     (ws + 16800064);    //        256 B
    int*      boff = (int*)     (ws + 16800320);    //        256 B

    hipMemsetAsync(cnt, 0, NN * sizeof(int), stream);
    gemm_hist<<<GEMM_BLOCKS + HIST_BLOCKS, 256, 0, stream>>>(
        nodes, W, b_lin, alpha, receivers, Xb, a01, cnt);
    scan_partial<<<SCAN_BLOCKS, 1024, 0, stream>>>(cnt, off, bsum);
    scan_mid    <<<1, 64, 0, stream>>>(bsum, boff, off);
    scan_add    <<<SCAN_BLOCKS, 1024, 0, stream>>>(off, boff, cnt);
    scatter  <<<(NE + 255) / 256, 256, 0, stream>>>(senders, receivers, off, cnt, srt);
    aggregate<<<(NN + 3) / 4, 256, 0, stream>>>(Xb, a01, off, srt, bias, out);
}

// Round 4
// 151.635 us; speedup vs baseline: 1.8717x; 1.1565x over previous
//
#include <hip/hip_runtime.h>

#define NN 50000
#define NE 800000
#define GEMM_BLOCKS 782      // ceil(50000/64)
#define HIST_BLOCKS 512
#define SCAN_BLOCKS 49       // ceil(50000/1024)

typedef unsigned short ushort_t;

__device__ __forceinline__ ushort_t f2bf(float f) {
    unsigned u = __float_as_uint(f);
    unsigned r = (u + 0x7fffu + ((u >> 16) & 1u)) >> 16;   // RNE
    return (ushort_t)r;
}
__device__ __forceinline__ float bf_lo(unsigned u) { return __uint_as_float(u << 16); }
__device__ __forceinline__ float bf_hi(unsigned u) { return __uint_as_float(u & 0xffff0000u); }
__device__ __forceinline__ float lrelu(float v) { return (v > 0.f) ? v : 0.2f * v; }

// ---- K1: fused  X = nodes@W + b (store bf16), a01 = lrelu(x·alpha) per node, + edge histogram
__global__ __launch_bounds__(256) void gemm_hist(
    const float* __restrict__ A,     // nodes [NN][128]
    const float* __restrict__ W,     // [128][128]
    const float* __restrict__ bl,    // [128]
    const float* __restrict__ alpha, // [256] (only first 128 used)
    const int*   __restrict__ rcv,   // [NE]
    ushort_t*    __restrict__ Xb,    // bf16 [NN][128]
    float2*      __restrict__ a01,   // [NN]
    int*         __restrict__ cnt)   // [NN]
{
    if (blockIdx.x >= GEMM_BLOCKS) {
        // ---- histogram blocks (independent work, overlapped with GEMM) ----
        int i = (blockIdx.x - GEMM_BLOCKS) * 256 + threadIdx.x;
        const int stride = HIST_BLOCKS * 256;
        for (; i < NE; i += stride) atomicAdd(&cnt[rcv[i]], 1);
        return;
    }

    __shared__ float As[32][68];    // transposed A tile: As[k][row]
    __shared__ float Bs[32][132];   // B tile: Bs[k][col]
    const int tid = threadIdx.x;
    const int tx = tid & 15, ty = tid >> 4;
    const int r0 = blockIdx.x * 64;
    float acc[4][8];
#pragma unroll
    for (int i = 0; i < 4; ++i)
#pragma unroll
        for (int j = 0; j < 8; ++j) acc[i][j] = 0.f;

    for (int k0 = 0; k0 < 128; k0 += 32) {
#pragma unroll
        for (int l = 0; l < 2; ++l) {
            int id = tid + l * 256;
            int row = id >> 3, c4 = id & 7;
            int gr = r0 + row;
            float4 v = make_float4(0.f, 0.f, 0.f, 0.f);
            if (gr < NN) v = *(const float4*)(A + gr * 128 + k0 + c4 * 4);
            As[c4 * 4 + 0][row] = v.x; As[c4 * 4 + 1][row] = v.y;
            As[c4 * 4 + 2][row] = v.z; As[c4 * 4 + 3][row] = v.w;
        }
#pragma unroll
        for (int l = 0; l < 4; ++l) {
            int id = tid + l * 256;
            int kk = id >> 5, c4 = id & 31;
            *(float4*)&Bs[kk][c4 * 4] = *(const float4*)(W + (k0 + kk) * 128 + c4 * 4);
        }
        __syncthreads();
#pragma unroll
        for (int kk = 0; kk < 32; ++kk) {
            float4 a4 = *(float4*)&As[kk][ty * 4];
            float4 b0 = *(float4*)&Bs[kk][tx * 4];
            float4 b1 = *(float4*)&Bs[kk][64 + tx * 4];
            float av[4] = {a4.x, a4.y, a4.z, a4.w};
            float bv[8] = {b0.x, b0.y, b0.z, b0.w, b1.x, b1.y, b1.z, b1.w};
#pragma unroll
            for (int i = 0; i < 4; ++i)
#pragma unroll
                for (int j = 0; j < 8; ++j)
                    acc[i][j] = fmaf(av[i], bv[j], acc[i][j]);
        }
        __syncthreads();
    }

    // epilogue: +bias, store bf16, per-row alpha dots reduced across the 16 tx lanes
    float4 blo = *(const float4*)(bl + tx * 4);
    float4 bhi = *(const float4*)(bl + 64 + tx * 4);
    float4 alo = *(const float4*)(alpha + tx * 4);        // head0 coeffs
    float4 ahi = *(const float4*)(alpha + 64 + tx * 4);   // head1 coeffs
#pragma unroll
    for (int i = 0; i < 4; ++i) {
        int gr = r0 + ty * 4 + i;
        bool ok = (gr < NN);
        float o0 = acc[i][0] + blo.x, o1 = acc[i][1] + blo.y;
        float o2 = acc[i][2] + blo.z, o3 = acc[i][3] + blo.w;
        float o4 = acc[i][4] + bhi.x, o5 = acc[i][5] + bhi.y;
        float o6 = acc[i][6] + bhi.z, o7 = acc[i][7] + bhi.w;
        if (ok) {
            ushort4 p0, p1;
            p0.x = f2bf(o0); p0.y = f2bf(o1); p0.z = f2bf(o2); p0.w = f2bf(o3);
            p1.x = f2bf(o4); p1.y = f2bf(o5); p1.z = f2bf(o6); p1.w = f2bf(o7);
            *(ushort4*)(Xb + (size_t)gr * 128 + tx * 4) = p0;
            *(ushort4*)(Xb + (size_t)gr * 128 + 64 + tx * 4) = p1;
        }
        float v0 = o0 * alo.x + o1 * alo.y + o2 * alo.z + o3 * alo.w;
        float v1 = o4 * ahi.x + o5 * ahi.y + o6 * ahi.z + o7 * ahi.w;
#pragma unroll
        for (int d = 1; d < 16; d <<= 1) {
            v0 += __shfl_xor(v0, d);
            v1 += __shfl_xor(v1, d);
        }
        if (ok && tx == 0) a01[gr] = make_float2(lrelu(v0), lrelu(v1));
    }
}

// ---- K2a: block-local exclusive scan (49 blocks x 1024, coalesced) ----------
__global__ __launch_bounds__(1024) void scan_partial(
    const int* __restrict__ cnt, int* __restrict__ off, int* __restrict__ bsum)
{
    __shared__ int wsum[16];
    const int t = threadIdx.x, lane = t & 63, wid = t >> 6;
    const int i = blockIdx.x * 1024 + t;
    int v = (i < NN) ? cnt[i] : 0;
    int incl = v;
#pragma unroll
    for (int d = 1; d < 64; d <<= 1) {
        int u = __shfl_up(incl, d);
        if (lane >= d) incl += u;
    }
    if (lane == 63) wsum[wid] = incl;
    __syncthreads();
    if (t < 16) {
        int w = wsum[t], wi = w;
#pragma unroll
        for (int d = 1; d < 16; d <<= 1) {
            int u = __shfl_up(wi, d);
            if (t >= d) wi += u;
        }
        wsum[t] = wi - w;                    // exclusive wave prefix
    }
    __syncthreads();
    int ex = wsum[wid] + (incl - v);         // block-local exclusive prefix
    if (i < NN) off[i] = ex;
    if (t == 1023) bsum[blockIdx.x] = ex + v;  // block total
}

// ---- K2b: scan the 49 block totals (one wave) -------------------------------
__global__ __launch_bounds__(64) void scan_mid(int* __restrict__ bsum, int* __restrict__ boff,
                                               int* __restrict__ off)
{
    const int t = threadIdx.x;
    int v = (t < SCAN_BLOCKS) ? bsum[t] : 0;
    int incl = v;
#pragma unroll
    for (int d = 1; d < 64; d <<= 1) {
        int u = __shfl_up(incl, d);
        if (t >= d) incl += u;
    }
    if (t < SCAN_BLOCKS) boff[t] = incl - v;
    if (t == 0) off[NN] = NE;
}

// ---- K2c: add block offsets; seed cnt as the scatter cursor (= off) ---------
__global__ __launch_bounds__(1024) void scan_add(
    int* __restrict__ off, const int* __restrict__ boff, int* __restrict__ cnt)
{
    const int i = blockIdx.x * 1024 + threadIdx.x;
    if (i < NN) {
        int o = off[i] + boff[blockIdx.x];
        off[i] = o;
        cnt[i] = o;                          // cursor starts at segment base
    }
}

// ---- K3: scatter sender ids into CSR order (cur holds absolute positions) ---
__global__ __launch_bounds__(256) void scatter(
    const int* __restrict__ snd, const int* __restrict__ rcv,
    int* __restrict__ cur, int* __restrict__ srt)
{
    int i = blockIdx.x * 256 + threadIdx.x;
    if (i >= NE) return;
    int p = atomicAdd(&cur[rcv[i]], 1);
    srt[p] = snd[i];
}

// ---- K4: per-node aggregation, 4 edges per wave-iteration -------------------
// wave = 4 subgroups x 16 lanes. Subgroup sub handles edge slot 4d+sub; lane l16
// covers channels 8*l16..8*l16+7 (one 16B bf16 load). head = l16>>2; heads 0/1
// softmax-weighted, heads 2/3 uniform mean. Cross-subgroup shfl_xor reduce.
__global__ __launch_bounds__(256) void aggregate(
    const ushort_t* __restrict__ Xb, const float2* __restrict__ a01,
    const int* __restrict__ off, const int* __restrict__ srt,
    const float* __restrict__ bias, float* __restrict__ out)
{
    const int n = blockIdx.x * 4 + (threadIdx.x >> 6);
    const int lane = threadIdx.x & 63;
    const int sub = lane >> 4;
    const int l16 = lane & 15;
    const int head = l16 >> 2;
    const bool soft = (head < 2);
    const int beg = off[n];
    const int deg = off[n + 1] - beg;
    const int total = deg + 1;               // + self loop

    float acc0 = 0.f, acc1 = 0.f, acc2 = 0.f, acc3 = 0.f;
    float acc4 = 0.f, acc5 = 0.f, acc6 = 0.f, acc7 = 0.f;
    float D = 0.f;

    for (int base = 0; base < total; base += 64) {
        int idx = base + lane;
        int sj = (idx < deg) ? srt[beg + idx] : n;   // slot idx==deg -> self loop
        float2 w2 = a01[sj];                          // 64 coalesced gathers
        int cnt4 = min(64, total - base);
        int iters = (cnt4 + 3) >> 2;
#pragma unroll 2
        for (int d = 0; d < iters; ++d) {
            int e = 4 * d + sub;                      // batch-local edge slot (<64)
            bool act = (e < cnt4);
            int   s   = __shfl(sj, e);
            float a0v = __shfl(w2.x, e);
            float a1v = __shfl(w2.y, e);
            float av  = (head == 0) ? a0v : a1v;
            float w   = act ? (soft ? __expf(av) : 1.0f) : 0.0f;
            D += w;
            uint4 u = *(const uint4*)(Xb + (size_t)s * 128 + l16 * 8);
            acc0 = fmaf(w, bf_lo(u.x), acc0);
            acc1 = fmaf(w, bf_hi(u.x), acc1);
            acc2 = fmaf(w, bf_lo(u.y), acc2);
            acc3 = fmaf(w, bf_hi(u.y), acc3);
            acc4 = fmaf(w, bf_lo(u.z), acc4);
            acc5 = fmaf(w, bf_hi(u.z), acc5);
            acc6 = fmaf(w, bf_lo(u.w), acc6);
            acc7 = fmaf(w, bf_hi(u.w), acc7);
        }
    }

    // reduce across the 4 subgroups (lanes l16, l16+16, l16+32, l16+48)
    acc0 += __shfl_xor(acc0, 16); acc0 += __shfl_xor(acc0, 32);
    acc1 += __shfl_xor(acc1, 16); acc1 += __shfl_xor(acc1, 32);
    acc2 += __shfl_xor(acc2, 16); acc2 += __shfl_xor(acc2, 32);
    acc3 += __shfl_xor(acc3, 16); acc3 += __shfl_xor(acc3, 32);
    acc4 += __shfl_xor(acc4, 16); acc4 += __shfl_xor(acc4, 32);
    acc5 += __shfl_xor(acc5, 16); acc5 += __shfl_xor(acc5, 32);
    acc6 += __shfl_xor(acc6, 16); acc6 += __shfl_xor(acc6, 32);
    acc7 += __shfl_xor(acc7, 16); acc7 += __shfl_xor(acc7, 32);
    D    += __shfl_xor(D, 16);    D    += __shfl_xor(D, 32);

    if (sub == 0) {
        float scale = soft ? (1.0f / D) : (1.0f / (float)total);
        float4 b0 = *(const float4*)(bias + l16 * 8);
        float4 b1 = *(const float4*)(bias + l16 * 8 + 4);
        float4 o0 = make_float4(acc0 * scale + b0.x, acc1 * scale + b0.y,
                                acc2 * scale + b0.z, acc3 * scale + b0.w);
        float4 o1 = make_float4(acc4 * scale + b1.x, acc5 * scale + b1.y,
                                acc6 * scale + b1.z, acc7 * scale + b1.w);
        *(float4*)(out + (size_t)n * 128 + l16 * 8)     = o0;
        *(float4*)(out + (size_t)n * 128 + l16 * 8 + 4) = o1;
    }
}

// ------------------------------------------------------------------------------
extern "C" void kernel_launch(void* const* d_in, const int* in_sizes, int n_in,
                              void* d_out, int out_size, void* d_ws, size_t ws_size,
                              hipStream_t stream)
{
    const float* nodes     = (const float*)d_in[0];
    const int*   senders   = (const int*)d_in[1];
    const int*   receivers = (const int*)d_in[2];
    const float* W         = (const float*)d_in[3];
    const float* b_lin     = (const float*)d_in[4];
    const float* alpha     = (const float*)d_in[5];
    const float* bias      = (const float*)d_in[6];
    float* out = (float*)d_out;

    char* ws = (char*)d_ws;
    ushort_t* Xb   = (ushort_t*)(ws);               // 12,800,000 B
    float2*   a01  = (float2*)  (ws + 12800000);    //    400,000 B
    int*      cnt  = (int*)     (ws + 13200000);    //    200,000 B
    int*      off  = (int*)     (ws + 13400000);    //    200,064 B (padded)
    int*      srt  = (int*)     (ws + 13600064);    //  3,200,000 B
    int*      bsum = (int*)     (ws + 16800064);    //        256 B
    int*      boff = (int*)     (ws + 16800320);    //        256 B

    hipMemsetAsync(cnt, 0, NN * sizeof(int), stream);
    gemm_hist<<<GEMM_BLOCKS + HIST_BLOCKS, 256, 0, stream>>>(
        nodes, W, b_lin, alpha, receivers, Xb, a01, cnt);
    scan_partial<<<SCAN_BLOCKS, 1024, 0, stream>>>(cnt, off, bsum);
    scan_mid    <<<1, 64, 0, stream>>>(bsum, boff, off);
    scan_add    <<<SCAN_BLOCKS, 1024, 0, stream>>>(off, boff, cnt);
    scatter  <<<(NE + 255) / 256, 256, 0, stream>>>(senders, receivers, cnt, srt);
    aggregate<<<(NN + 3) / 4, 256, 0, stream>>>(Xb, a01, off, srt, bias, out);
}